// Round 1
// baseline (1224.510 us; speedup 1.0000x reference)
//
#include <hip/hip_runtime.h>
#include <math.h>

#define S_LEN 128
#define D_DIM 768
#define P_PAIRS 1024

// ---------------------------------------------------------------------------
// Kernel 1: build X[P, 3*D] = [aspect_rep + opinion_rep, left, right]
// One block per pair p. 256 threads, each handles 3 columns (768 = 3*256).
// ---------------------------------------------------------------------------
__global__ __launch_bounds__(256) void build_x_kernel(
    const float* __restrict__ emb_all,   // [B,S,D]
    const int* __restrict__ span_masks,  // [B,S]
    const int* __restrict__ batch_idx,   // [P]
    const int* __restrict__ aspect_idx,  // [P]
    const int* __restrict__ opinion_idx, // [P]
    float* __restrict__ X)               // [P, 3*D]
{
    int p = blockIdx.x;
    int tid = threadIdx.x;
    __shared__ int s_li;
    int b = batch_idx[p];
    if (tid == 0) {
        int s = 0;
        for (int i = 0; i < S_LEN; ++i) s += span_masks[b * S_LEN + i];
        s_li = s - 1;
    }
    __syncthreads();
    int li = s_li;
    int a = aspect_idx[p];
    int o = opinion_idx[p];
    const float* emb = emb_all + (size_t)b * (S_LEN * D_DIM);
    bool both0 = (a == 0) && (o == 0);
    int bnd = (a != 0) ? a : o;          // boundary index (only used when !both0)
    int oe = (o == 0) ? li : o;          // effective opinion row

    size_t base = (size_t)p * (3 * D_DIM);

    #pragma unroll
    for (int j = 0; j < 3; ++j) {
        int d = tid + j * 256;
        float left, right;
        if (both0) {
            // left = mean over rows [1, li); right = max over rows [1, li)
            float s = 0.f;
            float m = -INFINITY;
            for (int r = 1; r < li; ++r) {
                float v = emb[r * D_DIM + d];
                s += v;
                m = fmaxf(m, v);
            }
            int cnt = (li - 1) > 0 ? (li - 1) : 1;
            left = s / (float)cnt;
            right = m;
        } else {
            if (bnd == 1) {
                left = emb[d];           // row 0
            } else {
                float m = -INFINITY;
                for (int r = 1; r < bnd; ++r) m = fmaxf(m, emb[r * D_DIM + d]);
                left = m;
            }
            if (bnd == li) {
                right = emb[(size_t)li * D_DIM + d];
            } else {
                float m = -INFINITY;
                for (int r = bnd; r < li; ++r) m = fmaxf(m, emb[r * D_DIM + d]);
                right = m;
            }
        }
        float ar  = emb[(size_t)a  * D_DIM + d];
        float orp = emb[(size_t)oe * D_DIM + d];
        X[base + d]             = ar + orp;
        X[base + D_DIM + d]     = left;
        X[base + 2 * D_DIM + d] = right;
    }
}

// ---------------------------------------------------------------------------
// Kernel 2: generic fp32 GEMM  C = act(A[M,K] @ B[K,N] + bias)
// 128x128 tile, BK=8, 256 threads, 8x8 per-thread register tile.
// M multiple of 128, K multiple of 8 (true for all 3 layers); N guarded.
// ---------------------------------------------------------------------------
#define BM 128
#define BN 128
#define BK 8
#define TM 8
#define TN 8

__global__ __launch_bounds__(256) void gemm_bias_act(
    const float* __restrict__ A, const float* __restrict__ Bw,
    const float* __restrict__ bias, float* __restrict__ C,
    int M, int N, int K, int do_relu)
{
    __shared__ float As[BK][BM + 4];   // +4 pad: write pattern -> <=2-way (free)
    __shared__ float Bs[BK][BN];
    int tid = threadIdx.x;
    int tx = tid & 15;
    int ty = tid >> 4;
    int row0 = blockIdx.y * BM + ty * TM;
    int col0 = blockIdx.x * BN + tx * TN;

    float acc[TM][TN];
    #pragma unroll
    for (int i = 0; i < TM; ++i)
        #pragma unroll
        for (int j = 0; j < TN; ++j) acc[i][j] = 0.f;

    for (int k0 = 0; k0 < K; k0 += BK) {
        #pragma unroll
        for (int i = 0; i < 4; ++i) {
            int idx = tid + i * 256;       // 0..1023
            int r = idx >> 3;              // 0..127
            int c = idx & 7;               // 0..7
            As[c][r] = A[(size_t)(blockIdx.y * BM + r) * K + k0 + c];
        }
        #pragma unroll
        for (int i = 0; i < 4; ++i) {
            int idx = tid + i * 256;
            int r = idx >> 7;              // 0..7
            int c = idx & 127;             // 0..127
            int col = blockIdx.x * BN + c;
            Bs[r][c] = (col < N) ? Bw[(size_t)(k0 + r) * N + col] : 0.f;
        }
        __syncthreads();
        #pragma unroll
        for (int kk = 0; kk < BK; ++kk) {
            float av[TM], bv[TN];
            #pragma unroll
            for (int i = 0; i < TM; ++i) av[i] = As[kk][ty * TM + i];
            #pragma unroll
            for (int j = 0; j < TN; ++j) bv[j] = Bs[kk][tx * TN + j];
            #pragma unroll
            for (int i = 0; i < TM; ++i)
                #pragma unroll
                for (int j = 0; j < TN; ++j)
                    acc[i][j] = fmaf(av[i], bv[j], acc[i][j]);
        }
        __syncthreads();
    }

    #pragma unroll
    for (int i = 0; i < TM; ++i) {
        int row = row0 + i;
        #pragma unroll
        for (int j = 0; j < TN; ++j) {
            int col = col0 + j;
            if (col < N) {
                float v = acc[i][j] + bias[col];
                if (do_relu) v = fmaxf(v, 0.f);
                C[(size_t)row * N + col] = v;
            }
        }
    }
}

// ---------------------------------------------------------------------------
extern "C" void kernel_launch(void* const* d_in, const int* in_sizes, int n_in,
                              void* d_out, int out_size, void* d_ws, size_t ws_size,
                              hipStream_t stream) {
    const float* emb        = (const float*)d_in[0];  // [16,128,768]
    const float* W1         = (const float*)d_in[1];  // [2304,1536]
    const float* b1         = (const float*)d_in[2];  // [1536]
    const float* W2         = (const float*)d_in[3];  // [1536,768]
    const float* b2         = (const float*)d_in[4];  // [768]
    const float* W3         = (const float*)d_in[5];  // [768,121]
    const float* b3         = (const float*)d_in[6];  // [121]
    const int* span_masks   = (const int*)d_in[7];    // [16,128]
    const int* batch_idx    = (const int*)d_in[8];    // [1024]
    const int* aspect_idx   = (const int*)d_in[9];    // [1024]
    const int* opinion_idx  = (const int*)d_in[10];   // [1024]
    float* out = (float*)d_out;                       // [1024,121]

    float* X  = (float*)d_ws;                          // 1024*2304 f32
    float* H1 = X  + (size_t)P_PAIRS * (3 * D_DIM);    // 1024*1536 f32
    float* H2 = H1 + (size_t)P_PAIRS * 1536;           // 1024*768  f32

    build_x_kernel<<<P_PAIRS, 256, 0, stream>>>(emb, span_masks, batch_idx,
                                                aspect_idx, opinion_idx, X);

    dim3 blk(256);
    dim3 g1((1536 + BN - 1) / BN, P_PAIRS / BM);
    gemm_bias_act<<<g1, blk, 0, stream>>>(X, W1, b1, H1, P_PAIRS, 1536, 2304, 1);

    dim3 g2((768 + BN - 1) / BN, P_PAIRS / BM);
    gemm_bias_act<<<g2, blk, 0, stream>>>(H1, W2, b2, H2, P_PAIRS, 768, 1536, 1);

    dim3 g3((121 + BN - 1) / BN, P_PAIRS / BM);
    gemm_bias_act<<<g3, blk, 0, stream>>>(H2, W3, b3, out, P_PAIRS, 121, 768, 0);
}

// Round 2
// 135.498 us; speedup vs baseline: 9.0371x; 9.0371x over previous
//
#include <hip/hip_runtime.h>
#include <hip/hip_bf16.h>
#include <math.h>

#define S_LEN 128
#define D_DIM 768
#define P_PAIRS 1024

typedef __attribute__((ext_vector_type(8))) short bf16x8;
typedef __attribute__((ext_vector_type(4))) float f32x4;

__device__ __forceinline__ ushort f2bf(float f) {
    __hip_bfloat16 h = __float2bfloat16(f);
    return *(ushort*)&h;
}

__device__ __forceinline__ void gload16(const void* g, void* l) {
    __builtin_amdgcn_global_load_lds(
        (const __attribute__((address_space(1))) void*)g,
        (__attribute__((address_space(3))) void*)l, 16, 0, 0);
}

// ---------------------------------------------------------------------------
// build X[P, 3*D] in bf16: [aspect+opinion, left, right]
// ---------------------------------------------------------------------------
__global__ __launch_bounds__(256) void build_x_kernel(
    const float* __restrict__ emb_all,   // [B,S,D]
    const int* __restrict__ span_masks,  // [B,S]
    const int* __restrict__ batch_idx,   // [P]
    const int* __restrict__ aspect_idx,  // [P]
    const int* __restrict__ opinion_idx, // [P]
    ushort* __restrict__ X)              // [P, 3*D] bf16
{
    int p = blockIdx.x;
    int tid = threadIdx.x;
    __shared__ int s_li;
    int b = batch_idx[p];
    if (tid == 0) {
        int s = 0;
        for (int i = 0; i < S_LEN; ++i) s += span_masks[b * S_LEN + i];
        s_li = s - 1;
    }
    __syncthreads();
    int li = s_li;
    int a = aspect_idx[p];
    int o = opinion_idx[p];
    const float* emb = emb_all + (size_t)b * (S_LEN * D_DIM);
    bool both0 = (a == 0) && (o == 0);
    int bnd = (a != 0) ? a : o;
    int oe = (o == 0) ? li : o;
    size_t base = (size_t)p * (3 * D_DIM);

    #pragma unroll
    for (int j = 0; j < 3; ++j) {
        int d = tid + j * 256;
        float left, right;
        if (both0) {
            float s = 0.f, m = -INFINITY;
            for (int r = 1; r < li; ++r) {
                float v = emb[r * D_DIM + d];
                s += v; m = fmaxf(m, v);
            }
            int cnt = (li - 1) > 0 ? (li - 1) : 1;
            left = s / (float)cnt;
            right = m;
        } else {
            if (bnd == 1) left = emb[d];
            else {
                float m = -INFINITY;
                for (int r = 1; r < bnd; ++r) m = fmaxf(m, emb[r * D_DIM + d]);
                left = m;
            }
            if (bnd == li) right = emb[(size_t)li * D_DIM + d];
            else {
                float m = -INFINITY;
                for (int r = bnd; r < li; ++r) m = fmaxf(m, emb[r * D_DIM + d]);
                right = m;
            }
        }
        float ar  = emb[(size_t)a  * D_DIM + d];
        float orp = emb[(size_t)oe * D_DIM + d];
        X[base + d]             = f2bf(ar + orp);
        X[base + D_DIM + d]     = f2bf(left);
        X[base + 2 * D_DIM + d] = f2bf(right);
    }
}

// ---------------------------------------------------------------------------
// transpose + f32->bf16:  in [K,N] f32  ->  out [Npad,K] bf16 (zero pad n>=N)
// grid: (K/32, Npad/32), 256 threads
// ---------------------------------------------------------------------------
__global__ __launch_bounds__(256) void transpose_to_bf16(
    const float* __restrict__ in, ushort* __restrict__ out,
    int K, int N, int Npad)
{
    __shared__ float tile[32][33];
    int k0 = blockIdx.x * 32, n0 = blockIdx.y * 32;
    int tx = threadIdx.x & 31, ty = threadIdx.x >> 5;  // ty 0..7
    #pragma unroll
    for (int i = 0; i < 4; ++i) {
        int k = k0 + ty + i * 8, n = n0 + tx;
        tile[ty + i * 8][tx] = (k < K && n < N) ? in[(size_t)k * N + n] : 0.f;
    }
    __syncthreads();
    #pragma unroll
    for (int i = 0; i < 4; ++i) {
        int n = n0 + ty + i * 8, k = k0 + tx;
        if (n < Npad && k < K) out[(size_t)n * K + k] = f2bf(tile[tx][ty + i * 8]);
    }
}

// ---------------------------------------------------------------------------
// MFMA bf16 GEMM: C[M,N] = act(A[M,K] @ Bt[N,K]^T + bias)
// BM=BN=BK=64, 256 threads = 4 waves (2x2), 2x2 16x16x32 frags per wave.
// global_load_lds(16B) staging, inverse-swizzled source + swizzled ds_read.
// ---------------------------------------------------------------------------
template<int WRITE_BF16, int RELU>
__global__ __launch_bounds__(256) void gemm_mfma(
    const ushort* __restrict__ A,    // [M,K] bf16
    const ushort* __restrict__ Bt,   // [Npad,K] bf16
    const float* __restrict__ bias,  // [N]
    void* __restrict__ Cout,         // [M,N]
    int M, int N, int K)
{
    __shared__ ushort lds[2][2][64 * 64];   // [buf][A=0/B=1][row*64+k]
    int tid = threadIdx.x;
    int lane = tid & 63;
    int w = tid >> 6;            // wave 0..3
    int wr = w >> 1, wc = w & 1; // 2x2 wave grid
    int rowBase = blockIdx.y * 64;
    int colBase = blockIdx.x * 64;

    // staging: wave w covers rows w*16 + i*8 + (lane>>3), i in {0,1}
    int srow  = lane >> 3;                              // 0..7
    int scolb = (((lane & 7) ^ srow) << 4);             // inverse-swizzled src byte
    const char* Abase = (const char*)(A  + (size_t)rowBase * K);
    const char* Bbase = (const char*)(Bt + (size_t)colBase * K);
    size_t rstride = (size_t)K * 2;

    f32x4 acc[2][2] = {};
    int nt = K >> 6;

    auto stage = [&](int buf, int t) {
        size_t kb0 = (size_t)(t << 7);  // t*64 bf16 = t*128 bytes
        #pragma unroll
        for (int i = 0; i < 2; ++i) {
            int r = w * 16 + i * 8 + srow;
            gload16(Abase + (size_t)r * rstride + kb0 + scolb,
                    &lds[buf][0][(w * 16 + i * 8) * 64]);
            gload16(Bbase + (size_t)r * rstride + kb0 + scolb,
                    &lds[buf][1][(w * 16 + i * 8) * 64]);
        }
    };

    auto ldfrag = [&](int buf, int ab, int sub, int kk) -> bf16x8 {
        int row = (ab ? wc : wr) * 32 + sub * 16 + (lane & 15);
        int kb = ((lane >> 4) << 4) + kk * 64;
        int addr = row * 128 + (kb ^ ((row & 7) << 4));
        return *(const bf16x8*)((const char*)&lds[buf][ab][0] + addr);
    };

    stage(0, 0);
    __syncthreads();
    int cur = 0;
    for (int t = 0; t < nt; ++t) {
        if (t + 1 < nt) stage(cur ^ 1, t + 1);
        bf16x8 af[2][2], bf[2][2];
        #pragma unroll
        for (int m = 0; m < 2; ++m)
            #pragma unroll
            for (int kk = 0; kk < 2; ++kk) af[m][kk] = ldfrag(cur, 0, m, kk);
        #pragma unroll
        for (int n = 0; n < 2; ++n)
            #pragma unroll
            for (int kk = 0; kk < 2; ++kk) bf[n][kk] = ldfrag(cur, 1, n, kk);
        #pragma unroll
        for (int m = 0; m < 2; ++m)
            #pragma unroll
            for (int n = 0; n < 2; ++n)
                #pragma unroll
                for (int kk = 0; kk < 2; ++kk)
                    acc[m][n] = __builtin_amdgcn_mfma_f32_16x16x32_bf16(
                        af[m][kk], bf[n][kk], acc[m][n], 0, 0, 0);
        __syncthreads();   // drains vmcnt(0) for staged loads + barrier
        cur ^= 1;
    }

    // epilogue: C/D layout col=lane&15, row=(lane>>4)*4+reg
    #pragma unroll
    for (int m = 0; m < 2; ++m) {
        #pragma unroll
        for (int n = 0; n < 2; ++n) {
            #pragma unroll
            for (int j = 0; j < 4; ++j) {
                int row = rowBase + wr * 32 + m * 16 + (lane >> 4) * 4 + j;
                int col = colBase + wc * 32 + n * 16 + (lane & 15);
                if (col < N && row < M) {
                    float v = acc[m][n][j] + bias[col];
                    if (RELU) v = fmaxf(v, 0.f);
                    if (WRITE_BF16)
                        ((ushort*)Cout)[(size_t)row * N + col] = f2bf(v);
                    else
                        ((float*)Cout)[(size_t)row * N + col] = v;
                }
            }
        }
    }
}

// ---------------------------------------------------------------------------
extern "C" void kernel_launch(void* const* d_in, const int* in_sizes, int n_in,
                              void* d_out, int out_size, void* d_ws, size_t ws_size,
                              hipStream_t stream) {
    const float* emb        = (const float*)d_in[0];
    const float* W1         = (const float*)d_in[1];  // [2304,1536]
    const float* b1         = (const float*)d_in[2];
    const float* W2         = (const float*)d_in[3];  // [1536,768]
    const float* b2         = (const float*)d_in[4];
    const float* W3         = (const float*)d_in[5];  // [768,121]
    const float* b3         = (const float*)d_in[6];
    const int* span_masks   = (const int*)d_in[7];
    const int* batch_idx    = (const int*)d_in[8];
    const int* aspect_idx   = (const int*)d_in[9];
    const int* opinion_idx  = (const int*)d_in[10];
    float* out = (float*)d_out;                       // [1024,121]

    // workspace (bf16), H2 aliases Xb (Xb dead after layer-1 GEMM)
    ushort* Xb  = (ushort*)d_ws;                        // 1024*2304
    ushort* H2  = Xb;                                   // 1024*768 (alias)
    ushort* W1t = Xb  + (size_t)1024 * 2304;            // 1536*2304
    ushort* W2t = W1t + (size_t)1536 * 2304;            // 768*1536
    ushort* W3t = W2t + (size_t)768 * 1536;             // 128*768
    ushort* H1  = W3t + (size_t)128 * 768;              // 1024*1536

    build_x_kernel<<<P_PAIRS, 256, 0, stream>>>(emb, span_masks, batch_idx,
                                                aspect_idx, opinion_idx, Xb);

    transpose_to_bf16<<<dim3(2304/32, 1536/32), 256, 0, stream>>>(W1, W1t, 2304, 1536, 1536);
    transpose_to_bf16<<<dim3(1536/32,  768/32), 256, 0, stream>>>(W2, W2t, 1536, 768, 768);
    transpose_to_bf16<<<dim3( 768/32,  128/32), 256, 0, stream>>>(W3, W3t, 768, 121, 128);

    gemm_mfma<1,1><<<dim3(1536/64, 1024/64), 256, 0, stream>>>(Xb, W1t, b1, H1, 1024, 1536, 2304);
    gemm_mfma<1,1><<<dim3( 768/64, 1024/64), 256, 0, stream>>>(H1, W2t, b2, H2, 1024, 768, 1536);
    gemm_mfma<0,0><<<dim3( 128/64, 1024/64), 256, 0, stream>>>(H2, W3t, b3, out, 1024, 121, 768);
}

// Round 3
// 111.342 us; speedup vs baseline: 10.9978x; 1.2170x over previous
//
#include <hip/hip_runtime.h>
#include <hip/hip_bf16.h>
#include <math.h>

#define S_LEN 128
#define D_DIM 768
#define P_PAIRS 1024
#define B_BATCH 16

typedef __attribute__((ext_vector_type(8))) short bf16x8;
typedef __attribute__((ext_vector_type(4))) float f32x4;

__device__ __forceinline__ ushort f2bf(float f) {
    __hip_bfloat16 h = __float2bfloat16(f);
    return *(ushort*)&h;
}

__device__ __forceinline__ void gload16(const void* g, void* l) {
    __builtin_amdgcn_global_load_lds(
        (const __attribute__((address_space(1))) void*)g,
        (__attribute__((address_space(3))) void*)l, 16, 0, 0);
}

// ---------------------------------------------------------------------------
// Per-batch precompute: prefix max (rows [1..r]), suffix max (rows [r..li-1]),
// mean over rows [1..li-1], plus li per batch.
// grid (B, 3), 256 threads; thread owns column d = blockIdx.y*256+tid.
// ---------------------------------------------------------------------------
__global__ __launch_bounds__(256) void precompute_kernel(
    const float* __restrict__ emb_all,   // [B,S,D]
    const int* __restrict__ span_masks,  // [B,S]
    ushort* __restrict__ pref,           // [B,S,D] bf16
    ushort* __restrict__ suf,            // [B,S,D] bf16
    ushort* __restrict__ meanv,          // [B,D]   bf16
    int* __restrict__ li_arr)            // [B]
{
    int b = blockIdx.x;
    int d = blockIdx.y * 256 + threadIdx.x;
    __shared__ int s_li;
    if (threadIdx.x == 0) {
        int s = 0;
        for (int i = 0; i < S_LEN; ++i) s += span_masks[b * S_LEN + i];
        s_li = s - 1;
        if (blockIdx.y == 0) li_arr[b] = s - 1;
    }
    __syncthreads();
    int li = s_li;
    const float* emb = emb_all + (size_t)b * S_LEN * D_DIM;
    ushort* prefb = pref + (size_t)b * S_LEN * D_DIM;
    ushort* sufb  = suf  + (size_t)b * S_LEN * D_DIM;

    float m = -INFINITY, s = 0.f;
    prefb[d] = f2bf(m);   // pref[0] = empty range
    #pragma unroll 4
    for (int r = 1; r < S_LEN; ++r) {
        float v = emb[r * D_DIM + d];
        m = fmaxf(m, v);
        prefb[r * D_DIM + d] = f2bf(m);
        if (r < li) s += v;
    }
    int cnt = (li - 1) > 0 ? (li - 1) : 1;
    meanv[b * D_DIM + d] = f2bf(s / (float)cnt);

    m = -INFINITY;
    #pragma unroll 4
    for (int r = S_LEN - 1; r >= 1; --r) {
        if (r < li) m = fmaxf(m, emb[r * D_DIM + d]);
        sufb[r * D_DIM + d] = f2bf(m);
    }
}

// ---------------------------------------------------------------------------
// build X[P, 3*D] bf16 via pure gathers from precomputed arrays.
// One block per pair, 256 threads x 3 columns.
// ---------------------------------------------------------------------------
__global__ __launch_bounds__(256) void build_x_kernel(
    const float* __restrict__ emb_all,
    const ushort* __restrict__ pref,
    const ushort* __restrict__ suf,
    const ushort* __restrict__ meanv,
    const int* __restrict__ li_arr,
    const int* __restrict__ batch_idx,
    const int* __restrict__ aspect_idx,
    const int* __restrict__ opinion_idx,
    ushort* __restrict__ X)              // [P, 3*D] bf16
{
    int p = blockIdx.x;
    int tid = threadIdx.x;
    int b = batch_idx[p];
    int li = li_arr[b];
    int a = aspect_idx[p];
    int o = opinion_idx[p];
    const float* emb = emb_all + (size_t)b * S_LEN * D_DIM;
    const ushort* prefb = pref + (size_t)b * S_LEN * D_DIM;
    const ushort* sufb  = suf  + (size_t)b * S_LEN * D_DIM;
    bool both0 = (a == 0) && (o == 0);
    int bnd = (a != 0) ? a : o;
    int oe = (o == 0) ? li : o;
    size_t base = (size_t)p * (3 * D_DIM);

    #pragma unroll
    for (int j = 0; j < 3; ++j) {
        int d = tid + j * 256;
        float ar  = emb[(size_t)a  * D_DIM + d];
        float orp = emb[(size_t)oe * D_DIM + d];
        ushort left, right;
        if (both0) {
            left  = meanv[b * D_DIM + d];
            right = prefb[(size_t)(li - 1) * D_DIM + d];
        } else {
            left  = (bnd == 1)  ? f2bf(emb[d])
                                : prefb[(size_t)(bnd - 1) * D_DIM + d];
            right = (bnd == li) ? f2bf(emb[(size_t)li * D_DIM + d])
                                : sufb[(size_t)bnd * D_DIM + d];
        }
        X[base + d]             = f2bf(ar + orp);
        X[base + D_DIM + d]     = left;
        X[base + 2 * D_DIM + d] = right;
    }
}

// ---------------------------------------------------------------------------
// transpose + f32->bf16:  in [K,N] f32  ->  out [Npad,K] bf16 (zero pad n>=N)
// ---------------------------------------------------------------------------
__global__ __launch_bounds__(256) void transpose_to_bf16(
    const float* __restrict__ in, ushort* __restrict__ out,
    int K, int N, int Npad)
{
    __shared__ float tile[32][33];
    int k0 = blockIdx.x * 32, n0 = blockIdx.y * 32;
    int tx = threadIdx.x & 31, ty = threadIdx.x >> 5;
    #pragma unroll
    for (int i = 0; i < 4; ++i) {
        int k = k0 + ty + i * 8, n = n0 + tx;
        tile[ty + i * 8][tx] = (k < K && n < N) ? in[(size_t)k * N + n] : 0.f;
    }
    __syncthreads();
    #pragma unroll
    for (int i = 0; i < 4; ++i) {
        int n = n0 + ty + i * 8, k = k0 + tx;
        if (n < Npad && k < K) out[(size_t)n * K + k] = f2bf(tile[tx][ty + i * 8]);
    }
}

// ---------------------------------------------------------------------------
// MFMA bf16 GEMM: C[M,N] = act(A[M,K] @ Bt[N,K]^T + bias)
// BM=BN=BK=64, 4 waves (2x2), 2x2 16x16x32 frags/wave, gload_lds staging.
// ---------------------------------------------------------------------------
template<int WRITE_BF16, int RELU>
__global__ __launch_bounds__(256) void gemm_mfma(
    const ushort* __restrict__ A,    // [M,K] bf16
    const ushort* __restrict__ Bt,   // [Npad,K] bf16
    const float* __restrict__ bias,  // [N]
    void* __restrict__ Cout,         // [M,N]
    int M, int N, int K)
{
    __shared__ ushort lds[2][2][64 * 64];
    int tid = threadIdx.x;
    int lane = tid & 63;
    int w = tid >> 6;
    int wr = w >> 1, wc = w & 1;
    int rowBase = blockIdx.y * 64;
    int colBase = blockIdx.x * 64;

    int srow  = lane >> 3;
    int scolb = (((lane & 7) ^ srow) << 4);
    const char* Abase = (const char*)(A  + (size_t)rowBase * K);
    const char* Bbase = (const char*)(Bt + (size_t)colBase * K);
    size_t rstride = (size_t)K * 2;

    f32x4 acc[2][2] = {};
    int nt = K >> 6;

    auto stage = [&](int buf, int t) {
        size_t kb0 = (size_t)(t << 7);
        #pragma unroll
        for (int i = 0; i < 2; ++i) {
            int r = w * 16 + i * 8 + srow;
            gload16(Abase + (size_t)r * rstride + kb0 + scolb,
                    &lds[buf][0][(w * 16 + i * 8) * 64]);
            gload16(Bbase + (size_t)r * rstride + kb0 + scolb,
                    &lds[buf][1][(w * 16 + i * 8) * 64]);
        }
    };

    auto ldfrag = [&](int buf, int ab, int sub, int kk) -> bf16x8 {
        int row = (ab ? wc : wr) * 32 + sub * 16 + (lane & 15);
        int kb = ((lane >> 4) << 4) + kk * 64;
        int addr = row * 128 + (kb ^ ((row & 7) << 4));
        return *(const bf16x8*)((const char*)&lds[buf][ab][0] + addr);
    };

    stage(0, 0);
    __syncthreads();
    int cur = 0;
    for (int t = 0; t < nt; ++t) {
        if (t + 1 < nt) stage(cur ^ 1, t + 1);
        bf16x8 af[2][2], bfr[2][2];
        #pragma unroll
        for (int m = 0; m < 2; ++m)
            #pragma unroll
            for (int kk = 0; kk < 2; ++kk) af[m][kk] = ldfrag(cur, 0, m, kk);
        #pragma unroll
        for (int n = 0; n < 2; ++n)
            #pragma unroll
            for (int kk = 0; kk < 2; ++kk) bfr[n][kk] = ldfrag(cur, 1, n, kk);
        #pragma unroll
        for (int m = 0; m < 2; ++m)
            #pragma unroll
            for (int n = 0; n < 2; ++n)
                #pragma unroll
                for (int kk = 0; kk < 2; ++kk)
                    acc[m][n] = __builtin_amdgcn_mfma_f32_16x16x32_bf16(
                        af[m][kk], bfr[n][kk], acc[m][n], 0, 0, 0);
        __syncthreads();
        cur ^= 1;
    }

    #pragma unroll
    for (int m = 0; m < 2; ++m) {
        #pragma unroll
        for (int n = 0; n < 2; ++n) {
            #pragma unroll
            for (int j = 0; j < 4; ++j) {
                int row = rowBase + wr * 32 + m * 16 + (lane >> 4) * 4 + j;
                int col = colBase + wc * 32 + n * 16 + (lane & 15);
                if (col < N && row < M) {
                    float v = acc[m][n][j] + bias[col];
                    if (RELU) v = fmaxf(v, 0.f);
                    if (WRITE_BF16)
                        ((ushort*)Cout)[(size_t)row * N + col] = f2bf(v);
                    else
                        ((float*)Cout)[(size_t)row * N + col] = v;
                }
            }
        }
    }
}

// ---------------------------------------------------------------------------
extern "C" void kernel_launch(void* const* d_in, const int* in_sizes, int n_in,
                              void* d_out, int out_size, void* d_ws, size_t ws_size,
                              hipStream_t stream) {
    const float* emb        = (const float*)d_in[0];
    const float* W1         = (const float*)d_in[1];  // [2304,1536]
    const float* b1         = (const float*)d_in[2];
    const float* W2         = (const float*)d_in[3];  // [1536,768]
    const float* b2         = (const float*)d_in[4];
    const float* W3         = (const float*)d_in[5];  // [768,121]
    const float* b3         = (const float*)d_in[6];
    const int* span_masks   = (const int*)d_in[7];
    const int* batch_idx    = (const int*)d_in[8];
    const int* aspect_idx   = (const int*)d_in[9];
    const int* opinion_idx  = (const int*)d_in[10];
    float* out = (float*)d_out;                       // [1024,121]

    // ---- workspace layout (ushort units) ----
    // [0]                Xb   1024*2304            (H2 aliases; dead after GEMM1)
    // [Xb+2359296] = scratch region, two phases:
    //   phase 1 (precompute+build_x): pref | suf | mean | li
    //   phase 2 (transposes+GEMMs):   W1t | W2t | W3t | H1   (overwrites phase 1)
    ushort* Xb  = (ushort*)d_ws;                        // 2,359,296 us
    ushort* H2  = Xb;
    ushort* SCR = Xb + (size_t)1024 * 2304;

    ushort* pref  = SCR;                                    // 1,572,864
    ushort* suf   = pref + (size_t)B_BATCH * S_LEN * D_DIM; // 1,572,864
    ushort* meanv = suf  + (size_t)B_BATCH * S_LEN * D_DIM; // 12,288
    int*    li_arr = (int*)(meanv + B_BATCH * D_DIM);       // 16 ints

    ushort* W1t = SCR;                                  // 3,538,944
    ushort* W2t = W1t + (size_t)1536 * 2304;            // 1,179,648
    ushort* W3t = W2t + (size_t)768 * 1536;             // 98,304
    ushort* H1  = W3t + (size_t)128 * 768;              // 1,572,864

    precompute_kernel<<<dim3(B_BATCH, 3), 256, 0, stream>>>(
        emb, span_masks, pref, suf, meanv, li_arr);

    build_x_kernel<<<P_PAIRS, 256, 0, stream>>>(
        emb, pref, suf, meanv, li_arr, batch_idx, aspect_idx, opinion_idx, Xb);

    transpose_to_bf16<<<dim3(2304/32, 1536/32), 256, 0, stream>>>(W1, W1t, 2304, 1536, 1536);
    transpose_to_bf16<<<dim3(1536/32,  768/32), 256, 0, stream>>>(W2, W2t, 1536, 768, 768);
    transpose_to_bf16<<<dim3( 768/32,  128/32), 256, 0, stream>>>(W3, W3t, 768, 121, 128);

    gemm_mfma<1,1><<<dim3(1536/64, 1024/64), 256, 0, stream>>>(Xb, W1t, b1, H1, 1024, 1536, 2304);
    gemm_mfma<1,1><<<dim3( 768/64, 1024/64), 256, 0, stream>>>(H1, W2t, b2, H2, 1024, 768, 1536);
    gemm_mfma<0,0><<<dim3( 128/64, 1024/64), 256, 0, stream>>>(H2, W3t, b3, out, 1024, 121, 768);
}

// Round 4
// 76.850 us; speedup vs baseline: 15.9338x; 1.4488x over previous
//
#include <hip/hip_runtime.h>
#include <hip/hip_bf16.h>
#include <math.h>

#define S_LEN 128
#define D_DIM 768
#define P_PAIRS 1024
#define B_BATCH 16

typedef __attribute__((ext_vector_type(8))) short bf16x8;
typedef __attribute__((ext_vector_type(4))) float f32x4;

__device__ __forceinline__ ushort f2bf(float f) {
    __hip_bfloat16 h = __float2bfloat16(f);
    return *(ushort*)&h;
}

__device__ __forceinline__ void gload16(const void* g, void* l) {
    __builtin_amdgcn_global_load_lds(
        (const __attribute__((address_space(1))) void*)g,
        (__attribute__((address_space(3))) void*)l, 16, 0, 0);
}

// ---------------------------------------------------------------------------
// Per-batch precompute (two-level row scan):
//   pref[b][r] = max(emb[b][1..r])          (pref[0] = -inf)
//   suf[b][r]  = max(emb[b][r..li-1])       (r >= 1; empty -> -inf)
//   mean[b]    = mean(emb[b][1..li-1])
// grid (B, D/64); 256 threads = 64 cols x 4 row-groups of 32 rows.
// Rows live in registers; cross-group combine via small LDS exchange.
// ---------------------------------------------------------------------------
__global__ __launch_bounds__(256) void precompute_kernel(
    const float* __restrict__ emb_all,   // [B,S,D]
    const int* __restrict__ span_masks,  // [B,S]
    ushort* __restrict__ pref,           // [B,S,D] bf16
    ushort* __restrict__ suf,            // [B,S,D] bf16
    ushort* __restrict__ meanv,          // [B,D]   bf16
    int* __restrict__ li_arr)            // [B]
{
    int b = blockIdx.x;
    int lane = threadIdx.x & 63;             // column within chunk
    int g = threadIdx.x >> 6;                // row-group 0..3
    int col = blockIdx.y * 64 + lane;
    int r0 = g * 32;

    __shared__ int s_li;
    __shared__ float lmax[4][64];
    __shared__ float lsuf[4][64];
    __shared__ float lsum[4][64];

    if (threadIdx.x == 0) {
        int s = 0;
        for (int i = 0; i < S_LEN; ++i) s += span_masks[b * S_LEN + i];
        s_li = s - 1;
        if (blockIdx.y == 0) li_arr[b] = s - 1;
    }
    __syncthreads();
    int li = s_li;

    const float* embb = emb_all + (size_t)b * S_LEN * D_DIM;
    ushort* prefb = pref + (size_t)b * S_LEN * D_DIM;
    ushort* sufb  = suf  + (size_t)b * S_LEN * D_DIM;

    // load 32 rows into registers (independent, coalesced)
    float v[32];
    #pragma unroll
    for (int r = 0; r < 32; ++r)
        v[r] = embb[(size_t)(r0 + r) * D_DIM + col];

    // group-local totals
    float wmax = -INFINITY, umax = -INFINITY, s = 0.f;
    #pragma unroll
    for (int r = 0; r < 32; ++r) {
        int gr = r0 + r;
        float w = (gr == 0) ? -INFINITY : v[r];
        wmax = fmaxf(wmax, w);
        bool in = (gr >= 1) && (gr < li);
        umax = fmaxf(umax, in ? v[r] : -INFINITY);
        s += in ? v[r] : 0.f;
    }
    lmax[g][lane] = wmax;
    lsuf[g][lane] = umax;
    lsum[g][lane] = s;
    __syncthreads();

    // cross-group bases
    float basep = -INFINITY;
    #pragma unroll
    for (int gg = 0; gg < 3; ++gg)
        if (gg < g) basep = fmaxf(basep, lmax[gg][lane]);
    float bases = -INFINITY;
    #pragma unroll
    for (int gg = 1; gg < 4; ++gg)
        if (gg > g) bases = fmaxf(bases, lsuf[gg][lane]);

    if (g == 0) {
        float tot = lsum[0][lane] + lsum[1][lane] + lsum[2][lane] + lsum[3][lane];
        int cnt = (li - 1) > 0 ? (li - 1) : 1;
        meanv[b * D_DIM + col] = f2bf(tot / (float)cnt);
    }

    // emit prefix
    float m = basep;
    #pragma unroll
    for (int r = 0; r < 32; ++r) {
        int gr = r0 + r;
        float w = (gr == 0) ? -INFINITY : v[r];
        m = fmaxf(m, w);
        prefb[(size_t)gr * D_DIM + col] = f2bf(m);
    }
    // emit suffix
    float m2 = bases;
    #pragma unroll
    for (int r = 31; r >= 0; --r) {
        int gr = r0 + r;
        bool in = (gr >= 1) && (gr < li);
        m2 = fmaxf(m2, in ? v[r] : -INFINITY);
        if (gr >= 1) sufb[(size_t)gr * D_DIM + col] = f2bf(m2);
    }
}

// ---------------------------------------------------------------------------
// build X[P, 3*D] bf16 via pure gathers from precomputed arrays.
// ---------------------------------------------------------------------------
__global__ __launch_bounds__(256) void build_x_kernel(
    const float* __restrict__ emb_all,
    const ushort* __restrict__ pref,
    const ushort* __restrict__ suf,
    const ushort* __restrict__ meanv,
    const int* __restrict__ li_arr,
    const int* __restrict__ batch_idx,
    const int* __restrict__ aspect_idx,
    const int* __restrict__ opinion_idx,
    ushort* __restrict__ X)              // [P, 3*D] bf16
{
    int p = blockIdx.x;
    int tid = threadIdx.x;
    int b = batch_idx[p];
    int li = li_arr[b];
    int a = aspect_idx[p];
    int o = opinion_idx[p];
    const float* emb = emb_all + (size_t)b * S_LEN * D_DIM;
    const ushort* prefb = pref + (size_t)b * S_LEN * D_DIM;
    const ushort* sufb  = suf  + (size_t)b * S_LEN * D_DIM;
    bool both0 = (a == 0) && (o == 0);
    int bnd = (a != 0) ? a : o;
    int oe = (o == 0) ? li : o;
    size_t base = (size_t)p * (3 * D_DIM);

    #pragma unroll
    for (int j = 0; j < 3; ++j) {
        int d = tid + j * 256;
        float ar  = emb[(size_t)a  * D_DIM + d];
        float orp = emb[(size_t)oe * D_DIM + d];
        ushort left, right;
        if (both0) {
            left  = meanv[b * D_DIM + d];
            right = prefb[(size_t)(li - 1) * D_DIM + d];
        } else {
            left  = (bnd == 1)  ? f2bf(emb[d])
                                : prefb[(size_t)(bnd - 1) * D_DIM + d];
            right = (bnd == li) ? f2bf(emb[(size_t)li * D_DIM + d])
                                : sufb[(size_t)bnd * D_DIM + d];
        }
        X[base + d]             = f2bf(ar + orp);
        X[base + D_DIM + d]     = left;
        X[base + 2 * D_DIM + d] = right;
    }
}

// ---------------------------------------------------------------------------
// transpose + f32->bf16:  in [K,N] f32  ->  out [Npad,K] bf16 (zero pad n>=N)
// ---------------------------------------------------------------------------
__global__ __launch_bounds__(256) void transpose_to_bf16(
    const float* __restrict__ in, ushort* __restrict__ out,
    int K, int N, int Npad)
{
    __shared__ float tile[32][33];
    int k0 = blockIdx.x * 32, n0 = blockIdx.y * 32;
    int tx = threadIdx.x & 31, ty = threadIdx.x >> 5;
    #pragma unroll
    for (int i = 0; i < 4; ++i) {
        int k = k0 + ty + i * 8, n = n0 + tx;
        tile[ty + i * 8][tx] = (k < K && n < N) ? in[(size_t)k * N + n] : 0.f;
    }
    __syncthreads();
    #pragma unroll
    for (int i = 0; i < 4; ++i) {
        int n = n0 + ty + i * 8, k = k0 + tx;
        if (n < Npad && k < K) out[(size_t)n * K + k] = f2bf(tile[tx][ty + i * 8]);
    }
}

// ---------------------------------------------------------------------------
// MFMA bf16 GEMM: C[M,N] = act(A[M,K] @ Bt[N,K]^T + bias)
// BM=BN=BK=64, 4 waves (2x2), 2x2 16x16x32 frags/wave, gload_lds staging.
// ---------------------------------------------------------------------------
template<int WRITE_BF16, int RELU>
__global__ __launch_bounds__(256) void gemm_mfma(
    const ushort* __restrict__ A,    // [M,K] bf16
    const ushort* __restrict__ Bt,   // [Npad,K] bf16
    const float* __restrict__ bias,  // [N]
    void* __restrict__ Cout,         // [M,N]
    int M, int N, int K)
{
    __shared__ ushort lds[2][2][64 * 64];
    int tid = threadIdx.x;
    int lane = tid & 63;
    int w = tid >> 6;
    int wr = w >> 1, wc = w & 1;
    int rowBase = blockIdx.y * 64;
    int colBase = blockIdx.x * 64;

    int srow  = lane >> 3;
    int scolb = (((lane & 7) ^ srow) << 4);
    const char* Abase = (const char*)(A  + (size_t)rowBase * K);
    const char* Bbase = (const char*)(Bt + (size_t)colBase * K);
    size_t rstride = (size_t)K * 2;

    f32x4 acc[2][2] = {};
    int nt = K >> 6;

    auto stage = [&](int buf, int t) {
        size_t kb0 = (size_t)(t << 7);
        #pragma unroll
        for (int i = 0; i < 2; ++i) {
            int r = w * 16 + i * 8 + srow;
            gload16(Abase + (size_t)r * rstride + kb0 + scolb,
                    &lds[buf][0][(w * 16 + i * 8) * 64]);
            gload16(Bbase + (size_t)r * rstride + kb0 + scolb,
                    &lds[buf][1][(w * 16 + i * 8) * 64]);
        }
    };

    auto ldfrag = [&](int buf, int ab, int sub, int kk) -> bf16x8 {
        int row = (ab ? wc : wr) * 32 + sub * 16 + (lane & 15);
        int kb = ((lane >> 4) << 4) + kk * 64;
        int addr = row * 128 + (kb ^ ((row & 7) << 4));
        return *(const bf16x8*)((const char*)&lds[buf][ab][0] + addr);
    };

    stage(0, 0);
    __syncthreads();
    int cur = 0;
    for (int t = 0; t < nt; ++t) {
        if (t + 1 < nt) stage(cur ^ 1, t + 1);
        bf16x8 af[2][2], bfr[2][2];
        #pragma unroll
        for (int m = 0; m < 2; ++m)
            #pragma unroll
            for (int kk = 0; kk < 2; ++kk) af[m][kk] = ldfrag(cur, 0, m, kk);
        #pragma unroll
        for (int n = 0; n < 2; ++n)
            #pragma unroll
            for (int kk = 0; kk < 2; ++kk) bfr[n][kk] = ldfrag(cur, 1, n, kk);
        #pragma unroll
        for (int m = 0; m < 2; ++m)
            #pragma unroll
            for (int n = 0; n < 2; ++n)
                #pragma unroll
                for (int kk = 0; kk < 2; ++kk)
                    acc[m][n] = __builtin_amdgcn_mfma_f32_16x16x32_bf16(
                        af[m][kk], bfr[n][kk], acc[m][n], 0, 0, 0);
        __syncthreads();
        cur ^= 1;
    }

    #pragma unroll
    for (int m = 0; m < 2; ++m) {
        #pragma unroll
        for (int n = 0; n < 2; ++n) {
            #pragma unroll
            for (int j = 0; j < 4; ++j) {
                int row = rowBase + wr * 32 + m * 16 + (lane >> 4) * 4 + j;
                int col = colBase + wc * 32 + n * 16 + (lane & 15);
                if (col < N && row < M) {
                    float v = acc[m][n][j] + bias[col];
                    if (RELU) v = fmaxf(v, 0.f);
                    if (WRITE_BF16)
                        ((ushort*)Cout)[(size_t)row * N + col] = f2bf(v);
                    else
                        ((float*)Cout)[(size_t)row * N + col] = v;
                }
            }
        }
    }
}

// ---------------------------------------------------------------------------
extern "C" void kernel_launch(void* const* d_in, const int* in_sizes, int n_in,
                              void* d_out, int out_size, void* d_ws, size_t ws_size,
                              hipStream_t stream) {
    const float* emb        = (const float*)d_in[0];
    const float* W1         = (const float*)d_in[1];  // [2304,1536]
    const float* b1         = (const float*)d_in[2];
    const float* W2         = (const float*)d_in[3];  // [1536,768]
    const float* b2         = (const float*)d_in[4];
    const float* W3         = (const float*)d_in[5];  // [768,121]
    const float* b3         = (const float*)d_in[6];
    const int* span_masks   = (const int*)d_in[7];
    const int* batch_idx    = (const int*)d_in[8];
    const int* aspect_idx   = (const int*)d_in[9];
    const int* opinion_idx  = (const int*)d_in[10];
    float* out = (float*)d_out;                       // [1024,121]

    // ---- workspace layout (ushort units) ----
    // [0]                Xb   1024*2304            (H2 aliases; dead after GEMM1)
    // [Xb+2359296] = scratch region, two phases:
    //   phase 1 (precompute+build_x): pref | suf | mean | li
    //   phase 2 (transposes+GEMMs):   W1t | W2t | W3t | H1   (overwrites phase 1)
    ushort* Xb  = (ushort*)d_ws;                        // 2,359,296 us
    ushort* H2  = Xb;
    ushort* SCR = Xb + (size_t)1024 * 2304;

    ushort* pref  = SCR;                                    // 1,572,864
    ushort* suf   = pref + (size_t)B_BATCH * S_LEN * D_DIM; // 1,572,864
    ushort* meanv = suf  + (size_t)B_BATCH * S_LEN * D_DIM; // 12,288
    int*    li_arr = (int*)(meanv + B_BATCH * D_DIM);       // 16 ints

    ushort* W1t = SCR;                                  // 3,538,944
    ushort* W2t = W1t + (size_t)1536 * 2304;            // 1,179,648
    ushort* W3t = W2t + (size_t)768 * 1536;             // 98,304
    ushort* H1  = W3t + (size_t)128 * 768;              // 1,572,864

    precompute_kernel<<<dim3(B_BATCH, D_DIM / 64), 256, 0, stream>>>(
        emb, span_masks, pref, suf, meanv, li_arr);

    build_x_kernel<<<P_PAIRS, 256, 0, stream>>>(
        emb, pref, suf, meanv, li_arr, batch_idx, aspect_idx, opinion_idx, Xb);

    transpose_to_bf16<<<dim3(2304/32, 1536/32), 256, 0, stream>>>(W1, W1t, 2304, 1536, 1536);
    transpose_to_bf16<<<dim3(1536/32,  768/32), 256, 0, stream>>>(W2, W2t, 1536, 768, 768);
    transpose_to_bf16<<<dim3( 768/32,  128/32), 256, 0, stream>>>(W3, W3t, 768, 121, 128);

    gemm_mfma<1,1><<<dim3(1536/64, 1024/64), 256, 0, stream>>>(Xb, W1t, b1, H1, 1024, 1536, 2304);
    gemm_mfma<1,1><<<dim3( 768/64, 1024/64), 256, 0, stream>>>(H1, W2t, b2, H2, 1024, 768, 1536);
    gemm_mfma<0,0><<<dim3( 128/64, 1024/64), 256, 0, stream>>>(H2, W3t, b3, out, 1024, 121, 768);
}

// Round 5
// 68.863 us; speedup vs baseline: 17.7819x; 1.1160x over previous
//
#include <hip/hip_runtime.h>
#include <hip/hip_bf16.h>
#include <math.h>

#define S_LEN 128
#define D_DIM 768
#define P_PAIRS 1024
#define B_BATCH 16

typedef __attribute__((ext_vector_type(8))) short bf16x8;
typedef __attribute__((ext_vector_type(4))) float f32x4;

__device__ __forceinline__ ushort f2bf(float f) {
    __hip_bfloat16 h = __float2bfloat16(f);
    return *(ushort*)&h;
}

__device__ __forceinline__ void gload16(const void* g, void* l) {
    __builtin_amdgcn_global_load_lds(
        (const __attribute__((address_space(1))) void*)g,
        (__attribute__((address_space(3))) void*)l, 16, 0, 0);
}

// ---------------------------------------------------------------------------
// Fused prep kernel.
//   blocks [0,192):    per-(batch, 64-col-chunk) span scan in LDS + X build
//   blocks [192,4896): the three weight transposes (f32 -> bf16, [K,N]->[N,K])
// All block groups are independent -> run concurrently in one launch.
// ---------------------------------------------------------------------------
#define PB_BLOCKS (B_BATCH * (D_DIM / 64))          // 192
#define T1_BLOCKS ((2304 / 32) * (1536 / 32))       // 3456
#define T2_BLOCKS ((1536 / 32) * (768 / 32))        // 1152
#define T3_BLOCKS ((768 / 32) * (128 / 32))         // 96

union SmemU {
    struct {
        float  semb[128][64];    // raw emb chunk (f32)
        ushort spref[128][64];   // prefix max  (bf16)
        ushort ssuf[128][64];    // suffix max  (bf16)
        ushort smean[64];
        float  lred[3][4][64];   // cross-group reduce: max / sufmax / sum
        int    li;
    } pb;
    float ttile[32][33];
};

__global__ __launch_bounds__(256) void fused_prep_kernel(
    const float* __restrict__ emb_all,   // [B,S,D]
    const int* __restrict__ span_masks,  // [B,S]
    const int* __restrict__ batch_idx,   // [P]
    const int* __restrict__ aspect_idx,  // [P]
    const int* __restrict__ opinion_idx, // [P]
    ushort* __restrict__ X,              // [P, 3*D] bf16
    const float* __restrict__ W1, ushort* __restrict__ W1t,
    const float* __restrict__ W2, ushort* __restrict__ W2t,
    const float* __restrict__ W3, ushort* __restrict__ W3t)
{
    __shared__ SmemU sm;
    int bid = blockIdx.x;
    int tid = threadIdx.x;

    if (bid < PB_BLOCKS) {
        // ================= span scan + X build =================
        int b = bid / (D_DIM / 64);
        int chunk = bid % (D_DIM / 64);
        int lane = tid & 63;
        int g = tid >> 6;           // wave/row-group 0..3
        int r0 = g * 32;
        int col = chunk * 64 + lane;

        if (tid == 0) {
            int s = 0;
            for (int i = 0; i < S_LEN; ++i) s += span_masks[b * S_LEN + i];
            sm.pb.li = s - 1;
        }
        __syncthreads();
        int li = sm.pb.li;

        const float* embb = emb_all + (size_t)b * S_LEN * D_DIM;

        // load 32 rows into regs, mirror to LDS f32
        float v[32];
        #pragma unroll
        for (int r = 0; r < 32; ++r) {
            v[r] = embb[(size_t)(r0 + r) * D_DIM + col];
            sm.pb.semb[r0 + r][lane] = v[r];
        }

        // group-local totals
        float wmax = -INFINITY, umax = -INFINITY, s = 0.f;
        #pragma unroll
        for (int r = 0; r < 32; ++r) {
            int gr = r0 + r;
            wmax = fmaxf(wmax, (gr == 0) ? -INFINITY : v[r]);
            bool in = (gr >= 1) && (gr < li);
            umax = fmaxf(umax, in ? v[r] : -INFINITY);
            s += in ? v[r] : 0.f;
        }
        sm.pb.lred[0][g][lane] = wmax;
        sm.pb.lred[1][g][lane] = umax;
        sm.pb.lred[2][g][lane] = s;
        __syncthreads();

        float basep = -INFINITY;
        #pragma unroll
        for (int gg = 0; gg < 3; ++gg)
            if (gg < g) basep = fmaxf(basep, sm.pb.lred[0][gg][lane]);
        float bases = -INFINITY;
        #pragma unroll
        for (int gg = 1; gg < 4; ++gg)
            if (gg > g) bases = fmaxf(bases, sm.pb.lred[1][gg][lane]);

        if (g == 0) {
            float tot = sm.pb.lred[2][0][lane] + sm.pb.lred[2][1][lane]
                      + sm.pb.lred[2][2][lane] + sm.pb.lred[2][3][lane];
            int cnt = (li - 1) > 0 ? (li - 1) : 1;
            sm.pb.smean[lane] = f2bf(tot / (float)cnt);
        }

        // emit prefix / suffix into LDS (bf16, same rounding as before)
        float m = basep;
        #pragma unroll
        for (int r = 0; r < 32; ++r) {
            int gr = r0 + r;
            m = fmaxf(m, (gr == 0) ? -INFINITY : v[r]);
            sm.pb.spref[gr][lane] = f2bf(m);
        }
        float m2 = bases;
        #pragma unroll
        for (int r = 31; r >= 0; --r) {
            int gr = r0 + r;
            bool in = (gr >= 1) && (gr < li);
            m2 = fmaxf(m2, in ? v[r] : -INFINITY);
            if (gr >= 1) sm.pb.ssuf[gr][lane] = f2bf(m2);
        }
        __syncthreads();

        // ---- pair loop: wave g scans pairs [g*256, g*256+256), ballot-style
        int pbase = g * 256;
        for (int c = 0; c < 256; c += 64) {
            int p = pbase + c + lane;
            int vb = batch_idx[p];
            int va = aspect_idx[p];
            int vo = opinion_idx[p];
            unsigned long long mask = __ballot(vb == b);
            while (mask) {
                int i = __ffsll((long long)mask) - 1;
                mask &= mask - 1;
                int pp = pbase + c + i;
                int a = __shfl(va, i);
                int o = __shfl(vo, i);
                bool both0 = (a == 0) && (o == 0);
                int bnd = (a != 0) ? a : o;
                int oe = (o == 0) ? li : o;
                float ar  = sm.pb.semb[a][lane];
                float orp = sm.pb.semb[oe][lane];
                ushort left, right;
                if (both0) {
                    left  = sm.pb.smean[lane];
                    right = sm.pb.spref[li - 1][lane];
                } else {
                    left  = (bnd == 1)  ? f2bf(sm.pb.semb[0][lane])
                                        : sm.pb.spref[bnd - 1][lane];
                    right = (bnd == li) ? f2bf(sm.pb.semb[li][lane])
                                        : sm.pb.ssuf[bnd][lane];
                }
                size_t base = (size_t)pp * (3 * D_DIM) + col;
                X[base]             = f2bf(ar + orp);
                X[base + D_DIM]     = left;
                X[base + 2 * D_DIM] = right;
            }
        }
    } else {
        // ================= weight transposes =================
        int tb = bid - PB_BLOCKS;
        const float* in; ushort* out; int K, N, Npad, bx, by;
        if (tb < T1_BLOCKS) {
            in = W1; out = W1t; K = 2304; N = 1536; Npad = 1536;
            bx = tb % (2304 / 32); by = tb / (2304 / 32);
        } else if (tb < T1_BLOCKS + T2_BLOCKS) {
            tb -= T1_BLOCKS;
            in = W2; out = W2t; K = 1536; N = 768; Npad = 768;
            bx = tb % (1536 / 32); by = tb / (1536 / 32);
        } else {
            tb -= T1_BLOCKS + T2_BLOCKS;
            in = W3; out = W3t; K = 768; N = 121; Npad = 128;
            bx = tb % (768 / 32); by = tb / (768 / 32);
        }
        int k0 = bx * 32, n0 = by * 32;
        int tx = tid & 31, ty = tid >> 5;
        #pragma unroll
        for (int i = 0; i < 4; ++i) {
            int k = k0 + ty + i * 8, n = n0 + tx;
            sm.ttile[ty + i * 8][tx] = (k < K && n < N) ? in[(size_t)k * N + n] : 0.f;
        }
        __syncthreads();
        #pragma unroll
        for (int i = 0; i < 4; ++i) {
            int n = n0 + ty + i * 8, k = k0 + tx;
            if (n < Npad && k < K) out[(size_t)n * K + k] = f2bf(sm.ttile[tx][ty + i * 8]);
        }
    }
}

// ---------------------------------------------------------------------------
// MFMA bf16 GEMM: C[M,N] = act(A[M,K] @ Bt[N,K]^T + bias)
// Tile BM x 64, BK=64, 4 waves (2x2), per-wave (BM/2)x32 output.
// 4-buffer depth-3 prefetch with counted vmcnt (never drains to 0 mid-loop).
// ---------------------------------------------------------------------------
template<int BM, int WRITE_BF16, int RELU>
__global__ __launch_bounds__(256) void gemm_mfma(
    const ushort* __restrict__ A,    // [M,K] bf16
    const ushort* __restrict__ Bt,   // [Npad,K] bf16
    const float* __restrict__ bias,  // [N]
    void* __restrict__ Cout,         // [M,N]
    int M, int N, int K)
{
    constexpr int FM  = BM / 32;       // m-frags per wave
    constexpr int AI  = BM / 32;       // A-stage instrs per wave
    constexpr int LPW = AI + 2;        // loads per wave per stage

    __shared__ ushort lds[4][(BM + 64) * 64];
    int tid = threadIdx.x;
    int lane = tid & 63;
    int w = tid >> 6;
    int wr = w >> 1, wc = w & 1;
    int rowBase = blockIdx.y * BM;
    int colBase = blockIdx.x * 64;

    int srow  = lane >> 3;                     // row within 8-row stage group
    int scolb = (((lane & 7) ^ srow) << 4);    // inverse-swizzled src byte col
    const char* Abase = (const char*)(A  + (size_t)rowBase * K);
    const char* Bbase = (const char*)(Bt + (size_t)colBase * K);
    size_t rstride = (size_t)K * 2;

    f32x4 acc[FM][2] = {};
    int nt = K >> 6;

    auto stage = [&](int buf, int t) {
        size_t kb0 = (size_t)t << 7;           // t*64 bf16 = t*128 bytes
        #pragma unroll
        for (int i = 0; i < AI; ++i) {
            int r = w * (AI * 8) + i * 8 + srow;
            gload16(Abase + (size_t)r * rstride + kb0 + scolb,
                    &lds[buf][(w * (AI * 8) + i * 8) * 64]);
        }
        #pragma unroll
        for (int i = 0; i < 2; ++i) {
            int r = w * 16 + i * 8 + srow;
            gload16(Bbase + (size_t)r * rstride + kb0 + scolb,
                    &lds[buf][(BM + w * 16 + i * 8) * 64]);
        }
    };

    stage(0, 0);
    stage(1, 1);
    stage(2, 2);

    for (int t = 0; t < nt; ++t) {
        int cur = t & 3;
        int ahead = nt - 1 - t;                // stages in flight beyond t
        if (ahead >= 2) {
            if constexpr (LPW == 6) asm volatile("s_waitcnt vmcnt(12)" ::: "memory");
            else                    asm volatile("s_waitcnt vmcnt(8)"  ::: "memory");
        } else if (ahead == 1) {
            if constexpr (LPW == 6) asm volatile("s_waitcnt vmcnt(6)" ::: "memory");
            else                    asm volatile("s_waitcnt vmcnt(4)" ::: "memory");
        } else {
            asm volatile("s_waitcnt vmcnt(0)" ::: "memory");
        }
        __builtin_amdgcn_s_barrier();
        __builtin_amdgcn_sched_barrier(0);

        if (t + 3 < nt) stage((t + 3) & 3, t + 3);

        const char* lb = (const char*)&lds[cur][0];
        int kq = (lane >> 4) << 4;
        bf16x8 af[FM][2], bfr[2][2];
        #pragma unroll
        for (int m = 0; m < FM; ++m) {
            int row = wr * (BM / 2) + m * 16 + (lane & 15);
            #pragma unroll
            for (int kk = 0; kk < 2; ++kk) {
                int addr = row * 128 + ((kq + kk * 64) ^ ((row & 7) << 4));
                af[m][kk] = *(const bf16x8*)(lb + addr);
            }
        }
        #pragma unroll
        for (int n = 0; n < 2; ++n) {
            int row = BM + wc * 32 + n * 16 + (lane & 15);
            #pragma unroll
            for (int kk = 0; kk < 2; ++kk) {
                int addr = row * 128 + ((kq + kk * 64) ^ ((row & 7) << 4));
                bfr[n][kk] = *(const bf16x8*)(lb + addr);
            }
        }
        __builtin_amdgcn_s_setprio(1);
        #pragma unroll
        for (int m = 0; m < FM; ++m)
            #pragma unroll
            for (int n = 0; n < 2; ++n)
                #pragma unroll
                for (int kk = 0; kk < 2; ++kk)
                    acc[m][n] = __builtin_amdgcn_mfma_f32_16x16x32_bf16(
                        af[m][kk], bfr[n][kk], acc[m][n], 0, 0, 0);
        __builtin_amdgcn_s_setprio(0);
    }

    #pragma unroll
    for (int m = 0; m < FM; ++m) {
        #pragma unroll
        for (int n = 0; n < 2; ++n) {
            #pragma unroll
            for (int j = 0; j < 4; ++j) {
                int row = rowBase + wr * (BM / 2) + m * 16 + (lane >> 4) * 4 + j;
                int col = colBase + wc * 32 + n * 16 + (lane & 15);
                if (col < N && row < M) {
                    float v = acc[m][n][j] + bias[col];
                    if (RELU) v = fmaxf(v, 0.f);
                    if (WRITE_BF16)
                        ((ushort*)Cout)[(size_t)row * N + col] = f2bf(v);
                    else
                        ((float*)Cout)[(size_t)row * N + col] = v;
                }
            }
        }
    }
}

// ---------------------------------------------------------------------------
extern "C" void kernel_launch(void* const* d_in, const int* in_sizes, int n_in,
                              void* d_out, int out_size, void* d_ws, size_t ws_size,
                              hipStream_t stream) {
    const float* emb        = (const float*)d_in[0];
    const float* W1         = (const float*)d_in[1];  // [2304,1536]
    const float* b1         = (const float*)d_in[2];
    const float* W2         = (const float*)d_in[3];  // [1536,768]
    const float* b2         = (const float*)d_in[4];
    const float* W3         = (const float*)d_in[5];  // [768,121]
    const float* b3         = (const float*)d_in[6];
    const int* span_masks   = (const int*)d_in[7];
    const int* batch_idx    = (const int*)d_in[8];
    const int* aspect_idx   = (const int*)d_in[9];
    const int* opinion_idx  = (const int*)d_in[10];
    float* out = (float*)d_out;                       // [1024,121]

    // workspace (ushort units); H2 aliases Xb (dead after GEMM1)
    ushort* Xb  = (ushort*)d_ws;                        // 2,359,296
    ushort* H2  = Xb;
    ushort* W1t = Xb  + (size_t)1024 * 2304;            // 3,538,944
    ushort* W2t = W1t + (size_t)1536 * 2304;            // 1,179,648
    ushort* W3t = W2t + (size_t)768 * 1536;             // 98,304
    ushort* H1  = W3t + (size_t)128 * 768;              // 1,572,864

    fused_prep_kernel<<<PB_BLOCKS + T1_BLOCKS + T2_BLOCKS + T3_BLOCKS, 256, 0, stream>>>(
        emb, span_masks, batch_idx, aspect_idx, opinion_idx, Xb,
        W1, W1t, W2, W2t, W3, W3t);

    gemm_mfma<128,1,1><<<dim3(1536/64, 1024/128), 256, 0, stream>>>(Xb, W1t, b1, H1, 1024, 1536, 2304);
    gemm_mfma< 64,1,1><<<dim3( 768/64, 1024/64),  256, 0, stream>>>(H1, W2t, b2, H2, 1024, 768, 1536);
    gemm_mfma< 64,0,0><<<dim3( 128/64, 1024/64),  256, 0, stream>>>(H2, W3t, b3, out, 1024, 121, 768);
}